// Round 16
// baseline (271.420 us; speedup 1.0000x reference)
//
#include <hip/hip_runtime.h>

// ---- problem constants ----
constexpr int BB   = 2;
constexpr int SEQ  = 1024;
constexpr int HIDC = 2048;
constexpr int NHEAD = 32;
constexpr int NKVH  = 8;
constexpr int HDIM  = 64;
constexpr int KBN   = 4096;
constexpr int TOPK  = 128;
constexpr int HCH   = 16;   // s-chunks for hcs partials

typedef unsigned short ushortt;
typedef __attribute__((ext_vector_type(8))) short short8;
typedef __attribute__((ext_vector_type(4))) float f32x4;

__device__ __forceinline__ ushortt f2b(float f){
  union { float f; unsigned u; } v; v.f = f;
  unsigned r = (v.u + 0x7FFFu + ((v.u >> 16) & 1u)) >> 16;
  return (ushortt)r;
}
__device__ __forceinline__ ushortt f2bfast(float f){   // round-half-up, 2 ops
  union { float f; unsigned u; } v; v.f = f;
  return (ushortt)((v.u + 0x8000u) >> 16);
}
__device__ __forceinline__ float b2f(ushortt b){
  union { unsigned u; float f; } v; v.u = ((unsigned)b) << 16;
  return v.f;
}
__device__ __forceinline__ void gload16(const void* g, void* l){
  __builtin_amdgcn_global_load_lds((const __attribute__((address_space(1))) void*)g,
                                   (__attribute__((address_space(3))) void*)l, 16, 0, 0);
}

// ---- prep: rope_table [0,256) + wsum [256,768) + cast_all [768,2816) fused ----
__global__ __launch_bounds__(256) void prep(const int* __restrict__ pos,
    const float* __restrict__ hs,
    const float* __restrict__ Wq, const float* __restrict__ Wqkb,
    const float* __restrict__ Wk, const float* __restrict__ Wv,
    const float* __restrict__ Wo,
    float* __restrict__ cosT, float* __restrict__ sinT, float* __restrict__ Wsum,
    ushortt* __restrict__ hsb, ushortt* __restrict__ Wcatb, ushortt* __restrict__ Wob)
{
  const int bid = blockIdx.x;
  if (bid < 256){
    int idx = bid*256 + threadIdx.x;       // (b*SEQ+s)*32 + i
    int i = idx & 31; int bs = idx >> 5;
    int p = pos[bs];
    double invf = exp(-(double)i * (log(10000.0) / 32.0));
    double ang = (double)p * invf;
    cosT[idx] = (float)cos(ang);
    sinT[idx] = (float)sin(ang);
  } else if (bid < 768){
    int idx = (bid-256)*256 + threadIdx.x;
    if (idx < 64*HIDC){
      int d = idx >> 11, k = idx & 2047;
      float acc = 0.f;
      for (int h2 = 0; h2 < NHEAD; ++h2) acc += Wqkb[(size_t)(h2*64 + d)*HIDC + k];
      Wsum[idx] = acc;
    }
  } else {
    const size_t NHS = (size_t)BB*SEQ*HIDC;
    const size_t NW  = (size_t)5120*HIDC;
    const size_t NO  = (size_t)HIDC*HIDC;
    const size_t total4 = (NHS + NW + NO) / 4;
    for (size_t i = (size_t)(bid-768)*256 + threadIdx.x; i < total4; i += (size_t)2048*256){
      size_t e = i * 4;
      const float* src; ushortt* dst;
      if (e < NHS){ src = hs + e; dst = hsb + e; }
      else if (e < NHS + NW){
        size_t ew = e - NHS; dst = Wcatb + ew;
        if      (ew < (size_t)2048*2048) src = Wq   + ew;
        else if (ew < (size_t)4096*2048) src = Wqkb + (ew - (size_t)2048*2048);
        else if (ew < (size_t)4608*2048) src = Wk   + (ew - (size_t)4096*2048);
        else                             src = Wv   + (ew - (size_t)4608*2048);
      } else { size_t eo = e - NHS - NW; src = Wo + eo; dst = Wob + eo; }
      float4 v = *(const float4*)src;
      dst[0] = f2b(v.x); dst[1] = f2b(v.y); dst[2] = f2b(v.z); dst[3] = f2b(v.w);
    }
  }
}

// ---- bf16 GEMM C = A @ Bt^T, 128x128 tile, BK=64, 2-deep counted-vmcnt pipeline,
// XOR chunk swizzle (source pre-swizzled for global_load_lds, swizzled ds_read):
// LDS row stride is 128B -> unswizzled would be 16-way bank conflict (G4) ----
template<int OUTF32>
__global__ __launch_bounds__(256) void gemm_bt(const ushortt* __restrict__ A,
                                               const ushortt* __restrict__ Bt,
                                               void* __restrict__ Cv,
                                               int M, int N, int K)
{
  __shared__ ushortt As[2][128*64];        // 32 KB
  __shared__ ushortt Bs[2][128*64];        // 32 KB
  const int tid = threadIdx.x;
  const int wave = tid >> 6, lane = tid & 63;
  const int bn = blockIdx.x, bm = blockIdx.y;
  const int wr = (wave >> 1) * 64, wc = (wave & 1) * 64;
  const int l4 = lane >> 4, lm = lane & 15;
  f32x4 acc[4][4] = {};
  // staging: lane = r8*8 + cb; each instruction covers 8 rows x 8 chunks (16B each);
  // global source chunk pre-swizzled by cb ^ r8 (LDS dest linear, row&7 == r8)
  const int r8 = lane >> 3, cb = lane & 7;
  const int scb = ((cb ^ r8) * 8);
  const ushortt* Ag0 = A  + (size_t)(bm*128 +      wave*16 +     r8)*K + scb;
  const ushortt* Ag1 = A  + (size_t)(bm*128 +      wave*16 + 8 + r8)*K + scb;
  const ushortt* Ag2 = A  + (size_t)(bm*128 + 64 + wave*16 +     r8)*K + scb;
  const ushortt* Ag3 = A  + (size_t)(bm*128 + 64 + wave*16 + 8 + r8)*K + scb;
  const ushortt* Bg0 = Bt + (size_t)(bn*128 +      wave*16 +     r8)*K + scb;
  const ushortt* Bg1 = Bt + (size_t)(bn*128 +      wave*16 + 8 + r8)*K + scb;
  const ushortt* Bg2 = Bt + (size_t)(bn*128 + 64 + wave*16 +     r8)*K + scb;
  const ushortt* Bg3 = Bt + (size_t)(bn*128 + 64 + wave*16 + 8 + r8)*K + scb;
  const int dA0 = (     wave*16    )*64;
  const int dA1 = (     wave*16 + 8)*64;
  const int dA2 = (64 + wave*16    )*64;
  const int dA3 = (64 + wave*16 + 8)*64;

  auto stage = [&](int k0, int bsel){      // 8 gloads per wave, own LDS slices
    gload16(Ag0 + k0, As[bsel] + dA0);
    gload16(Ag1 + k0, As[bsel] + dA1);
    gload16(Ag2 + k0, As[bsel] + dA2);
    gload16(Ag3 + k0, As[bsel] + dA3);
    gload16(Bg0 + k0, Bs[bsel] + dA0);
    gload16(Bg1 + k0, Bs[bsel] + dA1);
    gload16(Bg2 + k0, Bs[bsel] + dA2);
    gload16(Bg3 + k0, Bs[bsel] + dA3);
  };
  auto compute = [&](int bsel){
    const ushortt* a = As[bsel];
    const ushortt* b = Bs[bsel];
    #pragma unroll
    for (int kk=0;kk<2;++kk){
      const int co = (((kk*4 + l4) ^ (lm & 7)) * 8);   // swizzled chunk offset
      short8 af[4], bf_[4];
      #pragma unroll
      for (int mi=0;mi<4;++mi) af[mi]  = *(const short8*)&a[(wr + mi*16 + lm)*64 + co];
      #pragma unroll
      for (int ni=0;ni<4;++ni) bf_[ni] = *(const short8*)&b[(wc + ni*16 + lm)*64 + co];
      #pragma unroll
      for (int mi=0;mi<4;++mi)
        #pragma unroll
        for (int ni=0;ni<4;++ni)
          acc[mi][ni] = __builtin_amdgcn_mfma_f32_16x16x32_bf16(af[mi], bf_[ni], acc[mi][ni], 0, 0, 0);
    }
  };

  stage(0, 0);
  if (64 < K) stage(64, 1);
  int bsel = 0;
  for (int k0 = 0; k0 < K; k0 += 64){
    if (k0 + 64 < K) { asm volatile("s_waitcnt vmcnt(8)" ::: "memory"); }
    else             { asm volatile("s_waitcnt vmcnt(0)" ::: "memory"); }
    __builtin_amdgcn_sched_barrier(0);
    __builtin_amdgcn_s_barrier();          // all waves' buf[bsel] loads landed
    __builtin_amdgcn_sched_barrier(0);
    compute(bsel);
    __builtin_amdgcn_sched_barrier(0);
    __builtin_amdgcn_s_barrier();          // all waves done reading buf[bsel]
    __builtin_amdgcn_sched_barrier(0);
    if (k0 + 128 < K) stage(k0 + 128, bsel); // overwrite now-safe buffer
    bsel ^= 1;
  }

  const int cr = l4*4;
  #pragma unroll
  for (int mi=0;mi<4;++mi)
    #pragma unroll
    for (int ni=0;ni<4;++ni)
      #pragma unroll
      for (int r=0;r<4;++r){
        size_t row = (size_t)bm*128 + wr + mi*16 + cr + r;
        size_t col = (size_t)bn*128 + wc + ni*16 + lm;
        float v = acc[mi][ni][r];
        if (OUTF32) ((float*)Cv)[row*(size_t)N + col] = v;
        else        ((ushortt*)Cv)[row*(size_t)N + col] = f2b(v);
      }
}

// ---- rope + pack q/qkb only (pre-scaled by 1/8) ----
__global__ __launch_bounds__(256) void rope_pack(const ushortt* __restrict__ C1,
    const float* __restrict__ cosT, const float* __restrict__ sinT,
    ushortt* __restrict__ qr, ushortt* __restrict__ qkbr)
{
  const int row = blockIdx.x;              // b*SEQ + s
  const int b = row >> 10, s = row & 1023;
  const ushortt* cr = C1 + (size_t)row * 5120;
  const float* ct = cosT + (size_t)row * 32;
  const float* st = sinT + (size_t)row * 32;
  for (int j = threadIdx.x; j < 2048; j += 256){
    int h = j >> 6, d = j & 63, i = d & 31;
    float c = ct[i], sn = st[i];
    int jp = (d < 32) ? j + 32 : j - 32;
    float x  = b2f(cr[j]);
    float xp = b2f(cr[jp]);
    float o = (d < 32) ? (x*c - xp*sn) : (x*c + xp*sn);
    qr[((size_t)(b*NHEAD + h)*SEQ + s)*HDIM + d] = f2b(o * 0.125f);
    float y  = b2f(cr[2048 + j]);
    float yp = b2f(cr[2048 + jp]);
    float o2 = (d < 32) ? (y*c - yp*sn) : (y*c + yp*sn);
    qkbr[((size_t)(b*NHEAD + h)*SEQ + s)*HDIM + d] = f2b(o2 * 0.125f);
  }
}

// ---- K rope + V transpose pack; one (b,kvh,64-row s-chunk) per block ----
__global__ __launch_bounds__(256) void kv_pack(const ushortt* __restrict__ C1,
    const float* __restrict__ cosT, const float* __restrict__ sinT,
    ushortt* __restrict__ kr, ushortt* __restrict__ vt)
{
  const int bid = blockIdx.x;              // b*128 + kvh*16 + sc
  const int sc  = bid & 15;
  const int kvh = (bid >> 4) & 7;
  const int b   = bid >> 7;
  const int tid = threadIdx.x;
  __shared__ ushortt vs[64][66];           // padded: 2-way-free transposed reads
  #pragma unroll
  for (int it = 0; it < 2; ++it){
    int slot = it*256 + tid;               // [0,512): s = slot/8, dblk = slot%8
    int s = slot >> 3, dblk = slot & 7;
    const ushortt* base = C1 + (size_t)(b*SEQ + sc*64 + s)*5120 + kvh*64;
    short8 v = *(const short8*)(base + 4608 + dblk*8);
    *(short8*)&vs[s][dblk*8] = v;
    const ushortt* ksrc = base + 4096;
    const float* ct = cosT + ((size_t)b*SEQ + sc*64 + s)*32;
    const float* st = sinT + ((size_t)b*SEQ + sc*64 + s)*32;
    short8 out;
    #pragma unroll
    for (int e=0;e<8;++e){
      int d = dblk*8 + e, i = d & 31;
      int dp = (d < 32) ? d + 32 : d - 32;
      float x = b2f(ksrc[d]), xp = b2f(ksrc[dp]);
      float o = (d < 32) ? (x*ct[i] - xp*st[i]) : (x*ct[i] + xp*st[i]);
      out[e] = (short)f2b(o);
    }
    *(short8*)&kr[((size_t)(b*NKVH + kvh)*SEQ + sc*64 + s)*HDIM + dblk*8] = out;
  }
  __syncthreads();
  #pragma unroll
  for (int it = 0; it < 2; ++it){
    int slot = it*256 + tid;               // [0,512): d = slot/8, sblk = slot%8
    int d = slot >> 3, sblk = slot & 7;
    short8 out;
    #pragma unroll
    for (int e=0;e<8;++e) out[e] = (short)vs[sblk*8 + e][d];
    *(short8*)&vt[((size_t)(b*NKVH + kvh)*HDIM + d)*SEQ + sc*64 + sblk*8] = out;
  }
}

// ---- Hc/Hs partials: 1024 threads/block, 4 groups of 16 s each ----
__global__ __launch_bounds__(1024) void hcs_kernel(const float* __restrict__ hs,
    const float* __restrict__ cosT, const float* __restrict__ sinT,
    float* __restrict__ HcP, float* __restrict__ HsP)
{
  const int b = blockIdx.z, sc = blockIdx.y;
  const int tid = threadIdx.x;
  const int g = tid >> 8;                // group 0..3
  const int kl = tid & 255;              // k within block
  const int k = blockIdx.x*256 + kl;
  const int sbase = sc*64 + g*16;        // this group's 16-s slice
  __shared__ float cs[64*32];
  __shared__ float sn[64*32];
  __shared__ float accC[32*256];         // 32 KB
  __shared__ float accS[32*256];         // 32 KB
  for (int t = tid; t < 64*32; t += 1024){
    cs[t] = cosT[((size_t)b*SEQ + sc*64)*32 + t];
    sn[t] = sinT[((size_t)b*SEQ + sc*64)*32 + t];
  }
  __syncthreads();
  float ac[32], as_[32];
  #pragma unroll
  for (int i=0;i<32;++i){ ac[i]=0.f; as_[i]=0.f; }
  const float* hp = hs + ((size_t)b*SEQ + sbase)*HIDC + k;
  for (int s = 0; s < 16; ++s){
    float x = hp[(size_t)s*HIDC];
    const int so = (g*16 + s)*32;
    #pragma unroll
    for (int q=0;q<8;++q){
      float4 c4 = *(const float4*)&cs[so + q*4];
      float4 s4 = *(const float4*)&sn[so + q*4];
      ac[q*4+0]=fmaf(x,c4.x,ac[q*4+0]); as_[q*4+0]=fmaf(x,s4.x,as_[q*4+0]);
      ac[q*4+1]=fmaf(x,c4.y,ac[q*4+1]); as_[q*4+1]=fmaf(x,s4.y,as_[q*4+1]);
      ac[q*4+2]=fmaf(x,c4.z,ac[q*4+2]); as_[q*4+2]=fmaf(x,s4.z,as_[q*4+2]);
      ac[q*4+3]=fmaf(x,c4.w,ac[q*4+3]); as_[q*4+3]=fmaf(x,s4.w,as_[q*4+3]);
    }
  }
  __syncthreads();
  #pragma unroll
  for (int gg = 0; gg < 4; ++gg){
    if (g == gg){
      if (gg == 0){
        #pragma unroll
        for (int i=0;i<32;++i){ accC[i*256 + kl] = ac[i]; accS[i*256 + kl] = as_[i]; }
      } else {
        #pragma unroll
        for (int i=0;i<32;++i){ accC[i*256 + kl] += ac[i]; accS[i*256 + kl] += as_[i]; }
      }
    }
    __syncthreads();
  }
  for (int t = tid; t < 32*256; t += 1024){
    int i = t >> 8, kk = t & 255;
    size_t o = (((size_t)sc*BB + b)*32 + i)*HIDC + blockIdx.x*256 + kk;
    HcP[o] = accC[t];
    HsP[o] = accS[t];
  }
}

// ---- qsum[b][d] with inline HCH-partial reduction (f32 sc-ascending == hcs_reduce) ----
__global__ __launch_bounds__(256) void qsum_kernel(const float* __restrict__ HcP,
    const float* __restrict__ HsP, const float* __restrict__ Wsum, float* __restrict__ qsum)
{
  const int b = blockIdx.x >> 6, d = blockIdx.x & 63;
  const int i = d & 31;
  const size_t base = ((size_t)b*32 + i)*HIDC;
  const size_t scstride = (size_t)BB*32*HIDC;
  const float* w1 = Wsum + (size_t)d*HIDC;
  const float* w2 = Wsum + (size_t)((d < 32) ? d + 32 : d - 32)*HIDC;
  double acc = 0.0;
  for (int k = threadIdx.x; k < HIDC; k += 256){
    float hcv = 0.f, hsv = 0.f;
    #pragma unroll
    for (int sc = 0; sc < HCH; ++sc){
      hcv += HcP[(size_t)sc*scstride + base + k];
      hsv += HsP[(size_t)sc*scstride + base + k];
    }
    double t = (double)hcv * (double)w1[k];
    double u = (double)hsv * (double)w2[k];
    acc += (d < 32) ? (t - u) : (t + u);
  }
  __shared__ double red[256];
  red[threadIdx.x] = acc; __syncthreads();
  for (int s = 128; s > 0; s >>= 1){
    if (threadIdx.x < s) red[threadIdx.x] += red[threadIdx.x + s];
    __syncthreads();
  }
  if (threadIdx.x == 0) qsum[blockIdx.x] = (float)red[0];
}

// ---- ssum[b][n] = scale * qsum[b] . kb_keys[b][n]  (computed once) ----
__global__ void ssum_kernel(const float* __restrict__ qsum, const float* __restrict__ kbK,
                            float* __restrict__ sout){
  int idx = blockIdx.x*256 + threadIdx.x;
  if (idx >= BB*KBN) return;
  int b = idx >> 12;
  const float* q = qsum + b*64;
  const float* kk = kbK + (size_t)idx*64;
  double acc = 0.0;
  for (int d = 0; d < 64; ++d) acc += (double)q[d] * (double)kk[d];
  sout[idx] = (float)(acc * 0.125);
}

// ---- top-128 by exact rank counting (reads precomputed scores) ----
__global__ __launch_bounds__(256) void rank_topk(const float* __restrict__ sout,
                                                 int* __restrict__ sel)
{
  const int b = blockIdx.y, chunk = blockIdx.x;
  __shared__ unsigned long long keys[KBN];   // 32 KB
  const int tid = threadIdx.x;
  for (int i = tid; i < KBN; i += 256){
    float v = sout[(size_t)b*KBN + i];
    unsigned u = __float_as_uint(v);
    u = (u & 0x80000000u) ? ~u : (u | 0x80000000u);
    keys[i] = ((unsigned long long)u << 32) | (unsigned)(KBN - 1 - i);
  }
  __syncthreads();
  const int myi = chunk*256 + tid;
  const unsigned long long me = keys[myi];
  int rank = 0;
  for (int j = 0; j < KBN; j += 4){
    unsigned long long k0 = keys[j+0];
    unsigned long long k1 = keys[j+1];
    unsigned long long k2 = keys[j+2];
    unsigned long long k3 = keys[j+3];
    rank += (k0 > me) + (k1 > me) + (k2 > me) + (k3 > me);
  }
  if (rank < TOPK) sel[b*TOPK + rank] = myi;
}

// ---- gather: cast first-128 keys + gathered values^T to bf16 ----
__global__ __launch_bounds__(256) void gather_kb(const int* __restrict__ sel,
    const float* __restrict__ kbK, const float* __restrict__ kbV,
    ushortt* __restrict__ kbkb, ushortt* __restrict__ kbvtg)
{
  const int b = blockIdx.x;
  const int tid = threadIdx.x;
  for (int t = tid; t < TOPK*HDIM; t += 256){
    int j = t >> 6, d = t & 63;
    int idx = sel[b*TOPK + j];
    kbkb[(size_t)(b*TOPK + j)*HDIM + d] = f2b(kbK[((size_t)b*KBN + j)*HDIM + d]);
    kbvtg[((size_t)b*HDIM + d)*TOPK + j] = f2b(kbV[((size_t)b*KBN + idx)*HDIM + d]);
  }
}

// ---- fused flash attention: 4 waves/block, shared LDS K/V, 2-deep counted-vmcnt
// pipeline (raw barriers, vmcnt(4)); NO online max (|s| hard-bounded ~13) ----
__global__ __launch_bounds__(256) void attn_kernel(
    const ushortt* __restrict__ qr, const ushortt* __restrict__ qkbr,
    const ushortt* __restrict__ kr, const ushortt* __restrict__ vt,
    const ushortt* __restrict__ kbkb, const ushortt* __restrict__ kbvtg,
    const float* __restrict__ shf, ushortt* __restrict__ attno)
{
  const int i   = blockIdx.x;             // 512 blocks
  const int xcd = i & 7;                  // hw round-robin: wg i -> XCD i%8
  const int j   = i >> 3;                 // [0,64)
  const int chunk = xcd + 8*(j >> 5);     // [0,16): (b,kv) group
  const int pos   = j & 31;               // [0,32) within group
  const int b  = chunk >> 3;
  const int kv = chunk & 7;
  const int qtg = 7 - (pos >> 2);         // heavy q-tile-groups first
  const int h  = kv*4 + (pos & 3);
  const int tid = threadIdx.x;
  const int wave = tid >> 6, lane = tid & 63;
  const int l4 = lane >> 4, lm = lane & 15;
  const int qt = qtg*4 + wave;            // this wave's q-tile
  const int s0 = qt * 32;

  __shared__ ushortt Ks[2][64*64];        // 16 KB (swizzled)
  __shared__ ushortt Vs[2][64*64];        // 16 KB (swizzled)
  __shared__ ushortt P[4][32*72];         // per-wave P

  ushortt* Pw = P[wave];
  const ushortt* kbase = kr + (size_t)(b*NKVH + kv)*SEQ*HDIM;
  const ushortt* vbase = vt + (size_t)(b*NKVH + kv)*HDIM*SEQ;

  short8 aq[2][2], aqk[2][2];
  {
    const ushortt* qb  = qr   + ((size_t)(b*NHEAD + h)*SEQ + s0)*HDIM;
    const ushortt* qk2 = qkbr + ((size_t)(b*NHEAD + h)*SEQ + s0)*HDIM;
    #pragma unroll
    for (int mi=0;mi<2;++mi)
      #pragma unroll
      for (int kk=0;kk<2;++kk){
        int offa = (mi*16 + lm)*HDIM + kk*32 + l4*8;
        aq[mi][kk]  = *(const short8*)(qb  + offa);
        aqk[mi][kk] = *(const short8*)(qk2 + offa);
      }
  }
  f32x4 O[2][4] = {};
  float lrow[2][4];
  #pragma unroll
  for (int mi=0;mi<2;++mi)
    #pragma unroll
    for (int r=0;r<4;++r) lrow[mi][r] = 0.f;

  // stage one 64x64 K tile + V tile into LDS buffer bsel (4 gloads per wave)
  auto stageKV = [&](int t, int bsel){
    const int t0 = t*64;
    #pragma unroll
    for (int r2 = 0; r2 < 2; ++r2){
      int slot = r2*256 + wave*64 + lane;      // [0,512): row = slot/8, 16B-colblock = slot%8
      int row = slot >> 3, cb = slot & 7;
      int lcb = cb ^ (row & 7);                // inverse swizzle on global source
      ushortt* ldsK = &Ks[bsel][(size_t)(r2*256 + wave*64)*8];   // wave-uniform base
      ushortt* ldsV = &Vs[bsel][(size_t)(r2*256 + wave*64)*8];
      gload16(kbase + (size_t)(t0 + row)*HDIM + lcb*8, ldsK);
      gload16(vbase + (size_t)row*SEQ + t0 + lcb*8, ldsV);
    }
  };

  // no-max softmax accumulate: p = exp(s); P <- bf16(p); lrow += p
  auto update = [&](f32x4 (&lg)[2][4]){
    #pragma unroll
    for (int mi=0;mi<2;++mi)
      #pragma unroll
      for (int r=0;r<4;++r){
        float ps = 0.f;
        #pragma unroll
        for (int ni=0;ni<4;++ni){
          float p = __expf(lg[mi][ni][r]);
          ushortt pb = f2bfast(p);
          ps += b2f(pb);
          Pw[(mi*16 + l4*4 + r)*72 + ni*16 + lm] = pb;
        }
        lrow[mi][r] += ps;
      }
  };

  // compute one staged tile (no cross-wave barriers inside; P per-wave)
  auto computeTile = [&](int t, int bsel){
    const int t0 = t*64;
    const ushortt* Kb = Ks[bsel];
    const ushortt* Vb = Vs[bsel];
    f32x4 lg[2][4] = {};
    __builtin_amdgcn_s_setprio(1);
    #pragma unroll
    for (int kk=0;kk<2;++kk)
      #pragma unroll
      for (int ni=0;ni<4;++ni){
        int rr = ni*16 + lm;
        int c  = kk*4 + l4;
        short8 bk = *(const short8*)&Kb[rr*64 + ((c ^ (rr&7))*8)];
        lg[0][ni] = __builtin_amdgcn_mfma_f32_16x16x32_bf16(aq[0][kk], bk, lg[0][ni], 0,0,0);
        lg[1][ni] = __builtin_amdgcn_mfma_f32_16x16x32_bf16(aq[1][kk], bk, lg[1][ni], 0,0,0);
      }
    __builtin_amdgcn_s_setprio(0);
    const bool part = (t0 + 63 > s0);
    if (part){
      #pragma unroll
      for (int mi=0;mi<2;++mi)
        #pragma unroll
        for (int ni=0;ni<4;++ni)
          #pragma unroll
          for (int r=0;r<4;++r){
            int row = s0 + mi*16 + l4*4 + r;
            int col = t0 + ni*16 + lm;
            if (col > row) lg[mi][ni][r] = -1e30f;
          }
    }
    update(lg);
    __builtin_amdgcn_s_setprio(1);
    #pragma unroll
    for (int kk=0;kk<2;++kk){
      short8 pa0 = *(const short8*)&Pw[(lm)*72 + kk*32 + l4*8];
      short8 pa1 = *(const short8*)&Pw[(16 + lm)*72 + kk*32 + l4*8];
      #pragma unroll
      for (int di=0;di<4;++di){
        int rr = di*16 + lm;
        int c  = kk*4 + l4;
        short8 bv = *(const short8*)&Vb[rr*64 + ((c ^ (rr&7))*8)];
        O[0][di] = __builtin_amdgcn_mfma_f32_16x16x32_bf16(pa0, bv, O[0][di], 0,0,0);
        O[1][di] = __builtin_amdgcn_mfma_f32_16x16x32_bf16(pa1, bv, O[1][di], 0,0,0);
      }
    }
    __builtin_amdgcn_s_setprio(0);
  };

  const int nkt   = s0/64 + 1;          // this wave's causal tile count
  const int NTmax = 2*qtg + 2;          // block-uniform loop bound (= nkt of wave 3)

  stageKV(0, 0);
  if (NTmax > 1) stageKV(1, 1);
  for (int t = 0; t < NTmax; ++t){
    if (t < NTmax - 1) { asm volatile("s_waitcnt vmcnt(4)" ::: "memory"); }
    else               { asm volatile("s_waitcnt vmcnt(0)" ::: "memory"); }
    __builtin_amdgcn_sched_barrier(0);
    __builtin_amdgcn_s_barrier();        // buf[t&1] landed for all waves
    __builtin_amdgcn_sched_barrier(0);
    if (t < nkt) computeTile(t, t&1);
    __builtin_amdgcn_sched_barrier(0);
    __builtin_amdgcn_s_barrier();        // all waves done reading buf[t&1]
    __builtin_amdgcn_sched_barrier(0);
    if (t+2 < NTmax) stageKV(t+2, t&1);
  }

  // KB phase: 2 tiles of 64 columns, direct global reads (uniform across waves)
  {
    const float shift = shf[h];
    const ushortt* kbk = kbkb + (size_t)b*TOPK*HDIM;
    const ushortt* kbv = kbvtg + (size_t)b*HDIM*TOPK;
    #pragma unroll
    for (int jt=0;jt<2;++jt){
      const int j0 = jt*64;
      f32x4 lg[2][4] = {};
      __builtin_amdgcn_s_setprio(1);
      #pragma unroll
      for (int kk=0;kk<2;++kk)
        #pragma unroll
        for (int ni=0;ni<4;++ni){
          short8 bk = *(const short8*)(kbk + (size_t)(j0 + ni*16 + lm)*HDIM + kk*32 + l4*8);
          lg[0][ni] = __builtin_amdgcn_mfma_f32_16x16x32_bf16(aqk[0][kk], bk, lg[0][ni], 0,0,0);
          lg[1][ni] = __builtin_amdgcn_mfma_f32_16x16x32_bf16(aqk[1][kk], bk, lg[1][ni], 0,0,0);
        }
      __builtin_amdgcn_s_setprio(0);
      #pragma unroll
      for (int mi=0;mi<2;++mi)
        #pragma unroll
        for (int ni=0;ni<4;++ni)
          #pragma unroll
          for (int r=0;r<4;++r)
            lg[mi][ni][r] += shift;
      update(lg);
      __builtin_amdgcn_s_setprio(1);
      #pragma unroll
      for (int kk=0;kk<2;++kk){
        short8 pa0 = *(const short8*)&Pw[(lm)*72 + kk*32 + l4*8];
        short8 pa1 = *(const short8*)&Pw[(16 + lm)*72 + kk*32 + l4*8];
        #pragma unroll
        for (int di=0;di<4;++di){
          short8 bv = *(const short8*)(kbv + (size_t)(di*16 + lm)*TOPK + j0 + kk*32 + l4*8);
          O[0][di] = __builtin_amdgcn_mfma_f32_16x16x32_bf16(pa0, bv, O[0][di], 0,0,0);
          O[1][di] = __builtin_amdgcn_mfma_f32_16x16x32_bf16(pa1, bv, O[1][di], 0,0,0);
        }
      }
      __builtin_amdgcn_s_setprio(0);
    }
  }
  // finalize
  #pragma unroll
  for (int mi=0;mi<2;++mi)
    #pragma unroll
    for (int r=0;r<4;++r){
      float ls = lrow[mi][r];
      ls += __shfl_xor(ls, 1);
      ls += __shfl_xor(ls, 2);
      ls += __shfl_xor(ls, 4);
      ls += __shfl_xor(ls, 8);
      lrow[mi][r] = 1.0f / ls;
    }
  #pragma unroll
  for (int mi=0;mi<2;++mi)
    #pragma unroll
    for (int di=0;di<4;++di)
      #pragma unroll
      for (int r=0;r<4;++r){
        float o = O[mi][di][r] * lrow[mi][r];
        attno[(size_t)(b*SEQ + s0 + mi*16 + l4*4 + r)*HIDC + h*HDIM + di*16 + lm] = f2b(o);
      }
}

extern "C" void kernel_launch(void* const* d_in, const int* in_sizes, int n_in,
                              void* d_out, int out_size, void* d_ws, size_t ws_size,
                              hipStream_t stream)
{
  (void)in_sizes; (void)n_in; (void)out_size; (void)ws_size;
  const float* hs   = (const float*)d_in[0];
  const float* kbK  = (const float*)d_in[2];
  const float* kbV  = (const float*)d_in[3];
  const float* Wq   = (const float*)d_in[4];
  const float* Wqkb = (const float*)d_in[5];
  const float* Wk   = (const float*)d_in[6];
  const float* Wv   = (const float*)d_in[7];
  const float* Wo   = (const float*)d_in[8];
  const float* shf  = (const float*)d_in[9];
  const int*   pos  = (const int*)d_in[10];

  char* w = (char*)d_ws;
  size_t off = 0;
  auto alloc = [&](size_t bytes)->void*{
    void* p = w + off; off += (bytes + 255) & ~(size_t)255; return p;
  };
  ushortt* hsb   = (ushortt*)alloc((size_t)2048*2048*2);
  ushortt* Wcatb = (ushortt*)alloc((size_t)5120*2048*2);
  ushortt* Wob   = (ushortt*)alloc((size_t)2048*2048*2);
  ushortt* C1    = (ushortt*)alloc((size_t)2048*5120*2);
  float*   cosT  = (float*)alloc((size_t)BB*SEQ*32*4);
  float*   sinT  = (float*)alloc((size_t)BB*SEQ*32*4);
  ushortt* qr    = (ushortt*)alloc((size_t)BB*NHEAD*SEQ*HDIM*2);
  ushortt* qkbr  = (ushortt*)alloc((size_t)BB*NHEAD*SEQ*HDIM*2);
  ushortt* kr    = (ushortt*)alloc((size_t)BB*NKVH*SEQ*HDIM*2);
  ushortt* vt    = (ushortt*)alloc((size_t)BB*NKVH*SEQ*HDIM*2);
  float*   Wsum  = (float*)alloc((size_t)64*HIDC*4);
  float*   qsum  = (float*)alloc((size_t)BB*64*4);
  float*   sbuf  = (float*)alloc((size_t)BB*KBN*4);
  int*     sel   = (int*)alloc((size_t)BB*TOPK*4);
  ushortt* kbkb  = (ushortt*)alloc((size_t)BB*TOPK*HDIM*2);
  ushortt* kbvtg = (ushortt*)alloc((size_t)BB*HDIM*TOPK*2);
  ushortt* attno = (ushortt*)alloc((size_t)2048*2048*2);

  // hcs partials alias the C1 buffer (exact-ranking chain runs before gemm writes C1;
  // all launches are stream-serialized). Need 2 * HCH*BB*32*HIDC*4 = 16.8 MB <= 21 MB.
  float* HcP = (float*)C1;
  float* HsP = HcP + (size_t)HCH*BB*32*HIDC;

  prep<<<dim3(2816), dim3(256), 0, stream>>>(pos, hs, Wq, Wqkb, Wk, Wv, Wo,
                                             cosT, sinT, Wsum, hsb, Wcatb, Wob);
  hcs_kernel<<<dim3(8, HCH, BB), dim3(1024), 0, stream>>>(hs, cosT, sinT, HcP, HsP);
  qsum_kernel<<<dim3(128), dim3(256), 0, stream>>>(HcP, HsP, Wsum, qsum);
  ssum_kernel<<<dim3(32), dim3(256), 0, stream>>>(qsum, kbK, sbuf);
  rank_topk<<<dim3(KBN/256, BB), dim3(256), 0, stream>>>(sbuf, sel);
  gather_kb<<<dim3(BB), dim3(256), 0, stream>>>(sel, kbK, kbV, kbkb, kbvtg);
  gemm_bt<0><<<dim3(40, 16), dim3(256), 0, stream>>>(hsb, Wcatb, (void*)C1, 2048, 5120, 2048);
  rope_pack<<<dim3(2048), dim3(256), 0, stream>>>(C1, cosT, sinT, qr, qkbr);
  kv_pack<<<dim3(256), dim3(256), 0, stream>>>(C1, cosT, sinT, kr, vt);
  attn_kernel<<<dim3(512), dim3(256), 0, stream>>>(qr, qkbr, kr, vt, kbkb, kbvtg, shf, attno);
  gemm_bt<1><<<dim3(16, 16), dim3(256), 0, stream>>>(attno, Wob, d_out, 2048, 2048, 2048);
}

// Round 17
// 261.876 us; speedup vs baseline: 1.0364x; 1.0364x over previous
//
#include <hip/hip_runtime.h>

// ---- problem constants ----
constexpr int BB   = 2;
constexpr int SEQ  = 1024;
constexpr int HIDC = 2048;
constexpr int NHEAD = 32;
constexpr int NKVH  = 8;
constexpr int HDIM  = 64;
constexpr int KBN   = 4096;
constexpr int TOPK  = 128;
constexpr int HCH   = 16;   // s-chunks for hcs partials

typedef unsigned short ushortt;
typedef __attribute__((ext_vector_type(8))) short short8;
typedef __attribute__((ext_vector_type(4))) float f32x4;

__device__ __forceinline__ ushortt f2b(float f){
  union { float f; unsigned u; } v; v.f = f;
  unsigned r = (v.u + 0x7FFFu + ((v.u >> 16) & 1u)) >> 16;
  return (ushortt)r;
}
__device__ __forceinline__ ushortt f2bfast(float f){   // round-half-up, 2 ops
  union { float f; unsigned u; } v; v.f = f;
  return (ushortt)((v.u + 0x8000u) >> 16);
}
__device__ __forceinline__ float b2f(ushortt b){
  union { unsigned u; float f; } v; v.u = ((unsigned)b) << 16;
  return v.f;
}
__device__ __forceinline__ void gload16(const void* g, void* l){
  __builtin_amdgcn_global_load_lds((const __attribute__((address_space(1))) void*)g,
                                   (__attribute__((address_space(3))) void*)l, 16, 0, 0);
}

// ---- prep: rope_table [0,256) + wsum [256,768) + cast_all [768,2816) fused ----
__global__ __launch_bounds__(256) void prep(const int* __restrict__ pos,
    const float* __restrict__ hs,
    const float* __restrict__ Wq, const float* __restrict__ Wqkb,
    const float* __restrict__ Wk, const float* __restrict__ Wv,
    const float* __restrict__ Wo,
    float* __restrict__ cosT, float* __restrict__ sinT, float* __restrict__ Wsum,
    ushortt* __restrict__ hsb, ushortt* __restrict__ Wcatb, ushortt* __restrict__ Wob)
{
  const int bid = blockIdx.x;
  if (bid < 256){
    int idx = bid*256 + threadIdx.x;       // (b*SEQ+s)*32 + i
    int i = idx & 31; int bs = idx >> 5;
    int p = pos[bs];
    double invf = exp(-(double)i * (log(10000.0) / 32.0));
    double ang = (double)p * invf;
    cosT[idx] = (float)cos(ang);
    sinT[idx] = (float)sin(ang);
  } else if (bid < 768){
    int idx = (bid-256)*256 + threadIdx.x;
    if (idx < 64*HIDC){
      int d = idx >> 11, k = idx & 2047;
      float acc = 0.f;
      for (int h2 = 0; h2 < NHEAD; ++h2) acc += Wqkb[(size_t)(h2*64 + d)*HIDC + k];
      Wsum[idx] = acc;
    }
  } else {
    const size_t NHS = (size_t)BB*SEQ*HIDC;
    const size_t NW  = (size_t)5120*HIDC;
    const size_t NO  = (size_t)HIDC*HIDC;
    const size_t total4 = (NHS + NW + NO) / 4;
    for (size_t i = (size_t)(bid-768)*256 + threadIdx.x; i < total4; i += (size_t)2048*256){
      size_t e = i * 4;
      const float* src; ushortt* dst;
      if (e < NHS){ src = hs + e; dst = hsb + e; }
      else if (e < NHS + NW){
        size_t ew = e - NHS; dst = Wcatb + ew;
        if      (ew < (size_t)2048*2048) src = Wq   + ew;
        else if (ew < (size_t)4096*2048) src = Wqkb + (ew - (size_t)2048*2048);
        else if (ew < (size_t)4608*2048) src = Wk   + (ew - (size_t)4096*2048);
        else                             src = Wv   + (ew - (size_t)4608*2048);
      } else { size_t eo = e - NHS - NW; src = Wo + eo; dst = Wob + eo; }
      float4 v = *(const float4*)src;
      dst[0] = f2b(v.x); dst[1] = f2b(v.y); dst[2] = f2b(v.z); dst[3] = f2b(v.w);
    }
  }
}

// ---- bf16 GEMM C = A @ Bt^T, 128x128 tile, BK=32, 2-deep counted-vmcnt pipeline,
// XOR chunk swizzle: chunk' = c ^ ((row>>1)&3) spreads 16-lane b128 reads over all
// 8 bank slots (2-way aliasing = free). Source pre-swizzled, LDS dest linear. ----
template<int OUTF32>
__global__ __launch_bounds__(256) void gemm_bt(const ushortt* __restrict__ A,
                                               const ushortt* __restrict__ Bt,
                                               void* __restrict__ Cv,
                                               int M, int N, int K)
{
  __shared__ ushortt As[2][128*32];
  __shared__ ushortt Bs[2][128*32];
  const int tid = threadIdx.x;
  const int wave = tid >> 6, lane = tid & 63;
  const int bn = blockIdx.x, bm = blockIdx.y;
  const int wr = (wave >> 1) * 64, wc = (wave & 1) * 64;
  const int l4 = lane >> 4, lm = lane & 15;
  f32x4 acc[4][4] = {};
  const int srow = wave*16 + (lane >> 2);
  const int scol = ((lane & 3) ^ ((lane >> 3) & 3)) * 8;   // pre-swizzled source chunk
  const ushortt* Ag0 = A  + (size_t)(bm*128 + srow)*K + scol;
  const ushortt* Ag1 = Ag0 + (size_t)64*K;
  const ushortt* Bg0 = Bt + (size_t)(bn*128 + srow)*K + scol;
  const ushortt* Bg1 = Bg0 + (size_t)64*K;
  const int co = (l4 ^ ((lm >> 1) & 3)) * 8;               // swizzled read chunk
  const int soff = (wave*16)*32;

  auto stage = [&](int k0, int bsel){      // 4 gloads per wave, own LDS slice
    gload16(Ag0 + k0, As[bsel] + soff);
    gload16(Ag1 + k0, As[bsel] + 64*32 + soff);
    gload16(Bg0 + k0, Bs[bsel] + soff);
    gload16(Bg1 + k0, Bs[bsel] + 64*32 + soff);
  };
  auto compute = [&](int bsel){
    const ushortt* a = As[bsel];
    const ushortt* b = Bs[bsel];
    short8 af[4], bf_[4];
    #pragma unroll
    for (int mi=0;mi<4;++mi) af[mi]  = *(const short8*)&a[(wr + mi*16 + lm)*32 + co];
    #pragma unroll
    for (int ni=0;ni<4;++ni) bf_[ni] = *(const short8*)&b[(wc + ni*16 + lm)*32 + co];
    #pragma unroll
    for (int mi=0;mi<4;++mi)
      #pragma unroll
      for (int ni=0;ni<4;++ni)
        acc[mi][ni] = __builtin_amdgcn_mfma_f32_16x16x32_bf16(af[mi], bf_[ni], acc[mi][ni], 0, 0, 0);
  };

  stage(0, 0);
  if (32 < K) stage(32, 1);
  int bsel = 0;
  for (int k0 = 0; k0 < K; k0 += 32){
    if (k0 + 32 < K) { asm volatile("s_waitcnt vmcnt(4)" ::: "memory"); }
    else             { asm volatile("s_waitcnt vmcnt(0)" ::: "memory"); }
    __builtin_amdgcn_sched_barrier(0);
    __builtin_amdgcn_s_barrier();          // all waves' buf[bsel] loads landed
    __builtin_amdgcn_sched_barrier(0);
    compute(bsel);
    __builtin_amdgcn_sched_barrier(0);
    __builtin_amdgcn_s_barrier();          // all waves done reading buf[bsel]
    __builtin_amdgcn_sched_barrier(0);
    if (k0 + 64 < K) stage(k0 + 64, bsel); // overwrite now-safe buffer
    bsel ^= 1;
  }

  const int cr = l4*4;
  #pragma unroll
  for (int mi=0;mi<4;++mi)
    #pragma unroll
    for (int ni=0;ni<4;++ni)
      #pragma unroll
      for (int r=0;r<4;++r){
        size_t row = (size_t)bm*128 + wr + mi*16 + cr + r;
        size_t col = (size_t)bn*128 + wc + ni*16 + lm;
        float v = acc[mi][ni][r];
        if (OUTF32) ((float*)Cv)[row*(size_t)N + col] = v;
        else        ((ushortt*)Cv)[row*(size_t)N + col] = f2b(v);
      }
}

// ---- rope + pack q/qkb only (pre-scaled by 1/8) ----
__global__ __launch_bounds__(256) void rope_pack(const ushortt* __restrict__ C1,
    const float* __restrict__ cosT, const float* __restrict__ sinT,
    ushortt* __restrict__ qr, ushortt* __restrict__ qkbr)
{
  const int row = blockIdx.x;              // b*SEQ + s
  const int b = row >> 10, s = row & 1023;
  const ushortt* cr = C1 + (size_t)row * 5120;
  const float* ct = cosT + (size_t)row * 32;
  const float* st = sinT + (size_t)row * 32;
  for (int j = threadIdx.x; j < 2048; j += 256){
    int h = j >> 6, d = j & 63, i = d & 31;
    float c = ct[i], sn = st[i];
    int jp = (d < 32) ? j + 32 : j - 32;
    float x  = b2f(cr[j]);
    float xp = b2f(cr[jp]);
    float o = (d < 32) ? (x*c - xp*sn) : (x*c + xp*sn);
    qr[((size_t)(b*NHEAD + h)*SEQ + s)*HDIM + d] = f2b(o * 0.125f);
    float y  = b2f(cr[2048 + j]);
    float yp = b2f(cr[2048 + jp]);
    float o2 = (d < 32) ? (y*c - yp*sn) : (y*c + yp*sn);
    qkbr[((size_t)(b*NHEAD + h)*SEQ + s)*HDIM + d] = f2b(o2 * 0.125f);
  }
}

// ---- K rope + V transpose pack; one (b,kvh,64-row s-chunk) per block ----
__global__ __launch_bounds__(256) void kv_pack(const ushortt* __restrict__ C1,
    const float* __restrict__ cosT, const float* __restrict__ sinT,
    ushortt* __restrict__ kr, ushortt* __restrict__ vt)
{
  const int bid = blockIdx.x;              // b*128 + kvh*16 + sc
  const int sc  = bid & 15;
  const int kvh = (bid >> 4) & 7;
  const int b   = bid >> 7;
  const int tid = threadIdx.x;
  __shared__ ushortt vs[64][66];           // padded: 2-way-free transposed reads
  #pragma unroll
  for (int it = 0; it < 2; ++it){
    int slot = it*256 + tid;               // [0,512): s = slot/8, dblk = slot%8
    int s = slot >> 3, dblk = slot & 7;
    const ushortt* base = C1 + (size_t)(b*SEQ + sc*64 + s)*5120 + kvh*64;
    short8 v = *(const short8*)(base + 4608 + dblk*8);
    *(short8*)&vs[s][dblk*8] = v;
    const ushortt* ksrc = base + 4096;
    const float* ct = cosT + ((size_t)b*SEQ + sc*64 + s)*32;
    const float* st = sinT + ((size_t)b*SEQ + sc*64 + s)*32;
    short8 out;
    #pragma unroll
    for (int e=0;e<8;++e){
      int d = dblk*8 + e, i = d & 31;
      int dp = (d < 32) ? d + 32 : d - 32;
      float x = b2f(ksrc[d]), xp = b2f(ksrc[dp]);
      float o = (d < 32) ? (x*ct[i] - xp*st[i]) : (x*ct[i] + xp*st[i]);
      out[e] = (short)f2b(o);
    }
    *(short8*)&kr[((size_t)(b*NKVH + kvh)*SEQ + sc*64 + s)*HDIM + dblk*8] = out;
  }
  __syncthreads();
  #pragma unroll
  for (int it = 0; it < 2; ++it){
    int slot = it*256 + tid;               // [0,512): d = slot/8, sblk = slot%8
    int d = slot >> 3, sblk = slot & 7;
    short8 out;
    #pragma unroll
    for (int e=0;e<8;++e) out[e] = (short)vs[sblk*8 + e][d];
    *(short8*)&vt[((size_t)(b*NKVH + kvh)*HDIM + d)*SEQ + sc*64 + sblk*8] = out;
  }
}

// ---- Hc/Hs partials: 1024 threads/block, 4 groups of 16 s each ----
__global__ __launch_bounds__(1024) void hcs_kernel(const float* __restrict__ hs,
    const float* __restrict__ cosT, const float* __restrict__ sinT,
    float* __restrict__ HcP, float* __restrict__ HsP)
{
  const int b = blockIdx.z, sc = blockIdx.y;
  const int tid = threadIdx.x;
  const int g = tid >> 8;                // group 0..3
  const int kl = tid & 255;              // k within block
  const int k = blockIdx.x*256 + kl;
  const int sbase = sc*64 + g*16;        // this group's 16-s slice
  __shared__ float cs[64*32];
  __shared__ float sn[64*32];
  __shared__ float accC[32*256];         // 32 KB
  __shared__ float accS[32*256];         // 32 KB
  for (int t = tid; t < 64*32; t += 1024){
    cs[t] = cosT[((size_t)b*SEQ + sc*64)*32 + t];
    sn[t] = sinT[((size_t)b*SEQ + sc*64)*32 + t];
  }
  __syncthreads();
  float ac[32], as_[32];
  #pragma unroll
  for (int i=0;i<32;++i){ ac[i]=0.f; as_[i]=0.f; }
  const float* hp = hs + ((size_t)b*SEQ + sbase)*HIDC + k;
  for (int s = 0; s < 16; ++s){
    float x = hp[(size_t)s*HIDC];
    const int so = (g*16 + s)*32;
    #pragma unroll
    for (int q=0;q<8;++q){
      float4 c4 = *(const float4*)&cs[so + q*4];
      float4 s4 = *(const float4*)&sn[so + q*4];
      ac[q*4+0]=fmaf(x,c4.x,ac[q*4+0]); as_[q*4+0]=fmaf(x,s4.x,as_[q*4+0]);
      ac[q*4+1]=fmaf(x,c4.y,ac[q*4+1]); as_[q*4+1]=fmaf(x,s4.y,as_[q*4+1]);
      ac[q*4+2]=fmaf(x,c4.z,ac[q*4+2]); as_[q*4+2]=fmaf(x,s4.z,as_[q*4+2]);
      ac[q*4+3]=fmaf(x,c4.w,ac[q*4+3]); as_[q*4+3]=fmaf(x,s4.w,as_[q*4+3]);
    }
  }
  __syncthreads();
  #pragma unroll
  for (int gg = 0; gg < 4; ++gg){
    if (g == gg){
      if (gg == 0){
        #pragma unroll
        for (int i=0;i<32;++i){ accC[i*256 + kl] = ac[i]; accS[i*256 + kl] = as_[i]; }
      } else {
        #pragma unroll
        for (int i=0;i<32;++i){ accC[i*256 + kl] += ac[i]; accS[i*256 + kl] += as_[i]; }
      }
    }
    __syncthreads();
  }
  for (int t = tid; t < 32*256; t += 1024){
    int i = t >> 8, kk = t & 255;
    size_t o = (((size_t)sc*BB + b)*32 + i)*HIDC + blockIdx.x*256 + kk;
    HcP[o] = accC[t];
    HsP[o] = accS[t];
  }
}

// ---- qsum[b][d] with inline HCH-partial reduction (f32 sc-ascending == hcs_reduce) ----
__global__ __launch_bounds__(256) void qsum_kernel(const float* __restrict__ HcP,
    const float* __restrict__ HsP, const float* __restrict__ Wsum, float* __restrict__ qsum)
{
  const int b = blockIdx.x >> 6, d = blockIdx.x & 63;
  const int i = d & 31;
  const size_t base = ((size_t)b*32 + i)*HIDC;
  const size_t scstride = (size_t)BB*32*HIDC;
  const float* w1 = Wsum + (size_t)d*HIDC;
  const float* w2 = Wsum + (size_t)((d < 32) ? d + 32 : d - 32)*HIDC;
  double acc = 0.0;
  for (int k = threadIdx.x; k < HIDC; k += 256){
    float hcv = 0.f, hsv = 0.f;
    #pragma unroll
    for (int sc = 0; sc < HCH; ++sc){
      hcv += HcP[(size_t)sc*scstride + base + k];
      hsv += HsP[(size_t)sc*scstride + base + k];
    }
    double t = (double)hcv * (double)w1[k];
    double u = (double)hsv * (double)w2[k];
    acc += (d < 32) ? (t - u) : (t + u);
  }
  __shared__ double red[256];
  red[threadIdx.x] = acc; __syncthreads();
  for (int s = 128; s > 0; s >>= 1){
    if (threadIdx.x < s) red[threadIdx.x] += red[threadIdx.x + s];
    __syncthreads();
  }
  if (threadIdx.x == 0) qsum[blockIdx.x] = (float)red[0];
}

// ---- ssum[b][n] = scale * qsum[b] . kb_keys[b][n]  (computed once) ----
__global__ void ssum_kernel(const float* __restrict__ qsum, const float* __restrict__ kbK,
                            float* __restrict__ sout){
  int idx = blockIdx.x*256 + threadIdx.x;
  if (idx >= BB*KBN) return;
  int b = idx >> 12;
  const float* q = qsum + b*64;
  const float* kk = kbK + (size_t)idx*64;
  double acc = 0.0;
  for (int d = 0; d < 64; ++d) acc += (double)q[d] * (double)kk[d];
  sout[idx] = (float)(acc * 0.125);
}

// ---- top-128 by exact rank counting (reads precomputed scores) ----
__global__ __launch_bounds__(256) void rank_topk(const float* __restrict__ sout,
                                                 int* __restrict__ sel)
{
  const int b = blockIdx.y, chunk = blockIdx.x;
  __shared__ unsigned long long keys[KBN];   // 32 KB
  const int tid = threadIdx.x;
  for (int i = tid; i < KBN; i += 256){
    float v = sout[(size_t)b*KBN + i];
    unsigned u = __float_as_uint(v);
    u = (u & 0x80000000u) ? ~u : (u | 0x80000000u);
    keys[i] = ((unsigned long long)u << 32) | (unsigned)(KBN - 1 - i);
  }
  __syncthreads();
  const int myi = chunk*256 + tid;
  const unsigned long long me = keys[myi];
  int rank = 0;
  for (int j = 0; j < KBN; j += 4){
    unsigned long long k0 = keys[j+0];
    unsigned long long k1 = keys[j+1];
    unsigned long long k2 = keys[j+2];
    unsigned long long k3 = keys[j+3];
    rank += (k0 > me) + (k1 > me) + (k2 > me) + (k3 > me);
  }
  if (rank < TOPK) sel[b*TOPK + rank] = myi;
}

// ---- gather: cast first-128 keys + gathered values^T to bf16 ----
__global__ __launch_bounds__(256) void gather_kb(const int* __restrict__ sel,
    const float* __restrict__ kbK, const float* __restrict__ kbV,
    ushortt* __restrict__ kbkb, ushortt* __restrict__ kbvtg)
{
  const int b = blockIdx.x;
  const int tid = threadIdx.x;
  for (int t = tid; t < TOPK*HDIM; t += 256){
    int j = t >> 6, d = t & 63;
    int idx = sel[b*TOPK + j];
    kbkb[(size_t)(b*TOPK + j)*HDIM + d] = f2b(kbK[((size_t)b*KBN + j)*HDIM + d]);
    kbvtg[((size_t)b*HDIM + d)*TOPK + j] = f2b(kbV[((size_t)b*KBN + idx)*HDIM + d]);
  }
}

// ---- fused flash attention: 4 waves/block, shared LDS K/V, 2-deep counted-vmcnt
// pipeline (raw barriers, vmcnt(4)); NO online max (|s| hard-bounded ~13) ----
__global__ __launch_bounds__(256) void attn_kernel(
    const ushortt* __restrict__ qr, const ushortt* __restrict__ qkbr,
    const ushortt* __restrict__ kr, const ushortt* __restrict__ vt,
    const ushortt* __restrict__ kbkb, const ushortt* __restrict__ kbvtg,
    const float* __restrict__ shf, ushortt* __restrict__ attno)
{
  const int i   = blockIdx.x;             // 512 blocks
  const int xcd = i & 7;                  // hw round-robin: wg i -> XCD i%8
  const int j   = i >> 3;                 // [0,64)
  const int chunk = xcd + 8*(j >> 5);     // [0,16): (b,kv) group
  const int pos   = j & 31;               // [0,32) within group
  const int b  = chunk >> 3;
  const int kv = chunk & 7;
  const int qtg = 7 - (pos >> 2);         // heavy q-tile-groups first
  const int h  = kv*4 + (pos & 3);
  const int tid = threadIdx.x;
  const int wave = tid >> 6, lane = tid & 63;
  const int l4 = lane >> 4, lm = lane & 15;
  const int qt = qtg*4 + wave;            // this wave's q-tile
  const int s0 = qt * 32;

  __shared__ ushortt Ks[2][64*64];        // 16 KB (swizzled)
  __shared__ ushortt Vs[2][64*64];        // 16 KB (swizzled)
  __shared__ ushortt P[4][32*72];         // per-wave P

  ushortt* Pw = P[wave];
  const ushortt* kbase = kr + (size_t)(b*NKVH + kv)*SEQ*HDIM;
  const ushortt* vbase = vt + (size_t)(b*NKVH + kv)*HDIM*SEQ;

  short8 aq[2][2], aqk[2][2];
  {
    const ushortt* qb  = qr   + ((size_t)(b*NHEAD + h)*SEQ + s0)*HDIM;
    const ushortt* qk2 = qkbr + ((size_t)(b*NHEAD + h)*SEQ + s0)*HDIM;
    #pragma unroll
    for (int mi=0;mi<2;++mi)
      #pragma unroll
      for (int kk=0;kk<2;++kk){
        int offa = (mi*16 + lm)*HDIM + kk*32 + l4*8;
        aq[mi][kk]  = *(const short8*)(qb  + offa);
        aqk[mi][kk] = *(const short8*)(qk2 + offa);
      }
  }
  f32x4 O[2][4] = {};
  float lrow[2][4];
  #pragma unroll
  for (int mi=0;mi<2;++mi)
    #pragma unroll
    for (int r=0;r<4;++r) lrow[mi][r] = 0.f;

  // stage one 64x64 K tile + V tile into LDS buffer bsel (4 gloads per wave)
  auto stageKV = [&](int t, int bsel){
    const int t0 = t*64;
    #pragma unroll
    for (int r2 = 0; r2 < 2; ++r2){
      int slot = r2*256 + wave*64 + lane;      // [0,512): row = slot/8, 16B-colblock = slot%8
      int row = slot >> 3, cb = slot & 7;
      int lcb = cb ^ (row & 7);                // inverse swizzle on global source
      ushortt* ldsK = &Ks[bsel][(size_t)(r2*256 + wave*64)*8];   // wave-uniform base
      ushortt* ldsV = &Vs[bsel][(size_t)(r2*256 + wave*64)*8];
      gload16(kbase + (size_t)(t0 + row)*HDIM + lcb*8, ldsK);
      gload16(vbase + (size_t)row*SEQ + t0 + lcb*8, ldsV);
    }
  };

  // no-max softmax accumulate: p = exp(s); P <- bf16(p); lrow += p
  auto update = [&](f32x4 (&lg)[2][4]){
    #pragma unroll
    for (int mi=0;mi<2;++mi)
      #pragma unroll
      for (int r=0;r<4;++r){
        float ps = 0.f;
        #pragma unroll
        for (int ni=0;ni<4;++ni){
          float p = __expf(lg[mi][ni][r]);
          ushortt pb = f2bfast(p);
          ps += b2f(pb);
          Pw[(mi*16 + l4*4 + r)*72 + ni*16 + lm] = pb;
        }
        lrow[mi][r] += ps;
      }
  };

  // compute one staged tile (no cross-wave barriers inside; P per-wave)
  auto computeTile = [&](int t, int bsel){
    const int t0 = t*64;
    const ushortt* Kb = Ks[bsel];
    const ushortt* Vb = Vs[bsel];
    f32x4 lg[2][4] = {};
    __builtin_amdgcn_s_setprio(1);
    #pragma unroll
    for (int kk=0;kk<2;++kk)
      #pragma unroll
      for (int ni=0;ni<4;++ni){
        int rr = ni*16 + lm;
        int c  = kk*4 + l4;
        short8 bk = *(const short8*)&Kb[rr*64 + ((c ^ (rr&7))*8)];
        lg[0][ni] = __builtin_amdgcn_mfma_f32_16x16x32_bf16(aq[0][kk], bk, lg[0][ni], 0,0,0);
        lg[1][ni] = __builtin_amdgcn_mfma_f32_16x16x32_bf16(aq[1][kk], bk, lg[1][ni], 0,0,0);
      }
    __builtin_amdgcn_s_setprio(0);
    const bool part = (t0 + 63 > s0);
    if (part){
      #pragma unroll
      for (int mi=0;mi<2;++mi)
        #pragma unroll
        for (int ni=0;ni<4;++ni)
          #pragma unroll
          for (int r=0;r<4;++r){
            int row = s0 + mi*16 + l4*4 + r;
            int col = t0 + ni*16 + lm;
            if (col > row) lg[mi][ni][r] = -1e30f;
          }
    }
    update(lg);
    __builtin_amdgcn_s_setprio(1);
    #pragma unroll
    for (int kk=0;kk<2;++kk){
      short8 pa0 = *(const short8*)&Pw[(lm)*72 + kk*32 + l4*8];
      short8 pa1 = *(const short8*)&Pw[(16 + lm)*72 + kk*32 + l4*8];
      #pragma unroll
      for (int di=0;di<4;++di){
        int rr = di*16 + lm;
        int c  = kk*4 + l4;
        short8 bv = *(const short8*)&Vb[rr*64 + ((c ^ (rr&7))*8)];
        O[0][di] = __builtin_amdgcn_mfma_f32_16x16x32_bf16(pa0, bv, O[0][di], 0,0,0);
        O[1][di] = __builtin_amdgcn_mfma_f32_16x16x32_bf16(pa1, bv, O[1][di], 0,0,0);
      }
    }
    __builtin_amdgcn_s_setprio(0);
  };

  const int nkt   = s0/64 + 1;          // this wave's causal tile count
  const int NTmax = 2*qtg + 2;          // block-uniform loop bound (= nkt of wave 3)

  stageKV(0, 0);
  if (NTmax > 1) stageKV(1, 1);
  for (int t = 0; t < NTmax; ++t){
    if (t < NTmax - 1) { asm volatile("s_waitcnt vmcnt(4)" ::: "memory"); }
    else               { asm volatile("s_waitcnt vmcnt(0)" ::: "memory"); }
    __builtin_amdgcn_sched_barrier(0);
    __builtin_amdgcn_s_barrier();        // buf[t&1] landed for all waves
    __builtin_amdgcn_sched_barrier(0);
    if (t < nkt) computeTile(t, t&1);
    __builtin_amdgcn_sched_barrier(0);
    __builtin_amdgcn_s_barrier();        // all waves done reading buf[t&1]
    __builtin_amdgcn_sched_barrier(0);
    if (t+2 < NTmax) stageKV(t+2, t&1);
  }

  // KB phase: 2 tiles of 64 columns, direct global reads (uniform across waves)
  {
    const float shift = shf[h];
    const ushortt* kbk = kbkb + (size_t)b*TOPK*HDIM;
    const ushortt* kbv = kbvtg + (size_t)b*HDIM*TOPK;
    #pragma unroll
    for (int jt=0;jt<2;++jt){
      const int j0 = jt*64;
      f32x4 lg[2][4] = {};
      __builtin_amdgcn_s_setprio(1);
      #pragma unroll
      for (int kk=0;kk<2;++kk)
        #pragma unroll
        for (int ni=0;ni<4;++ni){
          short8 bk = *(const short8*)(kbk + (size_t)(j0 + ni*16 + lm)*HDIM + kk*32 + l4*8);
          lg[0][ni] = __builtin_amdgcn_mfma_f32_16x16x32_bf16(aqk[0][kk], bk, lg[0][ni], 0,0,0);
          lg[1][ni] = __builtin_amdgcn_mfma_f32_16x16x32_bf16(aqk[1][kk], bk, lg[1][ni], 0,0,0);
        }
      __builtin_amdgcn_s_setprio(0);
      #pragma unroll
      for (int mi=0;mi<2;++mi)
        #pragma unroll
        for (int ni=0;ni<4;++ni)
          #pragma unroll
          for (int r=0;r<4;++r)
            lg[mi][ni][r] += shift;
      update(lg);
      __builtin_amdgcn_s_setprio(1);
      #pragma unroll
      for (int kk=0;kk<2;++kk){
        short8 pa0 = *(const short8*)&Pw[(lm)*72 + kk*32 + l4*8];
        short8 pa1 = *(const short8*)&Pw[(16 + lm)*72 + kk*32 + l4*8];
        #pragma unroll
        for (int di=0;di<4;++di){
          short8 bv = *(const short8*)(kbv + (size_t)(di*16 + lm)*TOPK + j0 + kk*32 + l4*8);
          O[0][di] = __builtin_amdgcn_mfma_f32_16x16x32_bf16(pa0, bv, O[0][di], 0,0,0);
          O[1][di] = __builtin_amdgcn_mfma_f32_16x16x32_bf16(pa1, bv, O[1][di], 0,0,0);
        }
      }
      __builtin_amdgcn_s_setprio(0);
    }
  }
  // finalize
  #pragma unroll
  for (int mi=0;mi<2;++mi)
    #pragma unroll
    for (int r=0;r<4;++r){
      float ls = lrow[mi][r];
      ls += __shfl_xor(ls, 1);
      ls += __shfl_xor(ls, 2);
      ls += __shfl_xor(ls, 4);
      ls += __shfl_xor(ls, 8);
      lrow[mi][r] = 1.0f / ls;
    }
  #pragma unroll
  for (int mi=0;mi<2;++mi)
    #pragma unroll
    for (int di=0;di<4;++di)
      #pragma unroll
      for (int r=0;r<4;++r){
        float o = O[mi][di][r] * lrow[mi][r];
        attno[(size_t)(b*SEQ + s0 + mi*16 + l4*4 + r)*HIDC + h*HDIM + di*16 + lm] = f2b(o);
      }
}

extern "C" void kernel_launch(void* const* d_in, const int* in_sizes, int n_in,
                              void* d_out, int out_size, void* d_ws, size_t ws_size,
                              hipStream_t stream)
{
  (void)in_sizes; (void)n_in; (void)out_size; (void)ws_size;
  const float* hs   = (const float*)d_in[0];
  const float* kbK  = (const float*)d_in[2];
  const float* kbV  = (const float*)d_in[3];
  const float* Wq   = (const float*)d_in[4];
  const float* Wqkb = (const float*)d_in[5];
  const float* Wk   = (const float*)d_in[6];
  const float* Wv   = (const float*)d_in[7];
  const float* Wo   = (const float*)d_in[8];
  const float* shf  = (const float*)d_in[9];
  const int*   pos  = (const int*)d_in[10];

  char* w = (char*)d_ws;
  size_t off = 0;
  auto alloc = [&](size_t bytes)->void*{
    void* p = w + off; off += (bytes + 255) & ~(size_t)255; return p;
  };
  ushortt* hsb   = (ushortt*)alloc((size_t)2048*2048*2);
  ushortt* Wcatb = (ushortt*)alloc((size_t)5120*2048*2);
  ushortt* Wob   = (ushortt*)alloc((size_t)2048*2048*2);
  ushortt* C1    = (ushortt*)alloc((size_t)2048*5120*2);
  float*   cosT  = (float*)alloc((size_t)BB*SEQ*32*4);
  float*   sinT  = (float*)alloc((size_t)BB*SEQ*32*4);
  ushortt* qr    = (ushortt*)alloc((size_t)BB*NHEAD*SEQ*HDIM*2);
  ushortt* qkbr  = (ushortt*)alloc((size_t)BB*NHEAD*SEQ*HDIM*2);
  ushortt* kr    = (ushortt*)alloc((size_t)BB*NKVH*SEQ*HDIM*2);
  ushortt* vt    = (ushortt*)alloc((size_t)BB*NKVH*SEQ*HDIM*2);
  float*   Wsum  = (float*)alloc((size_t)64*HIDC*4);
  float*   qsum  = (float*)alloc((size_t)BB*64*4);
  float*   sbuf  = (float*)alloc((size_t)BB*KBN*4);
  int*     sel   = (int*)alloc((size_t)BB*TOPK*4);
  ushortt* kbkb  = (ushortt*)alloc((size_t)BB*TOPK*HDIM*2);
  ushortt* kbvtg = (ushortt*)alloc((size_t)BB*HDIM*TOPK*2);
  ushortt* attno = (ushortt*)alloc((size_t)2048*2048*2);

  // hcs partials alias the C1 buffer (exact-ranking chain runs before gemm writes C1;
  // all launches are stream-serialized). Need 2 * HCH*BB*32*HIDC*4 = 16.8 MB <= 21 MB.
  float* HcP = (float*)C1;
  float* HsP = HcP + (size_t)HCH*BB*32*HIDC;

  prep<<<dim3(2816), dim3(256), 0, stream>>>(pos, hs, Wq, Wqkb, Wk, Wv, Wo,
                                             cosT, sinT, Wsum, hsb, Wcatb, Wob);
  hcs_kernel<<<dim3(8, HCH, BB), dim3(1024), 0, stream>>>(hs, cosT, sinT, HcP, HsP);
  qsum_kernel<<<dim3(128), dim3(256), 0, stream>>>(HcP, HsP, Wsum, qsum);
  ssum_kernel<<<dim3(32), dim3(256), 0, stream>>>(qsum, kbK, sbuf);
  rank_topk<<<dim3(KBN/256, BB), dim3(256), 0, stream>>>(sbuf, sel);
  gather_kb<<<dim3(BB), dim3(256), 0, stream>>>(sel, kbK, kbV, kbkb, kbvtg);
  gemm_bt<0><<<dim3(40, 16), dim3(256), 0, stream>>>(hsb, Wcatb, (void*)C1, 2048, 5120, 2048);
  rope_pack<<<dim3(2048), dim3(256), 0, stream>>>(C1, cosT, sinT, qr, qkbr);
  kv_pack<<<dim3(256), dim3(256), 0, stream>>>(C1, cosT, sinT, kr, vt);
  attn_kernel<<<dim3(512), dim3(256), 0, stream>>>(qr, qkbr, kr, vt, kbkb, kbvtg, shf, attno);
  gemm_bt<1><<<dim3(16, 16), dim3(256), 0, stream>>>(attno, Wob, d_out, 2048, 2048, 2048);
}